// Round 4
// baseline (330.580 us; speedup 1.0000x reference)
//
#include <hip/hip_runtime.h>

// GCNConv forward: out = D^{-1/2} (A + I) D^{-1/2} (x @ W) + b
// N = 1,000,000 nodes (< 2^20), E = 4,000,000 edges, F = 16.
//
// Pipeline (tiles = 2048 consecutive dst nodes, 489 tiles):
//   K0 init:  cursor[b] = b*CAP (line-padded cursors)
//   K1 bin:   per 8192-edge block: edges staged in REGISTERS, LDS hist
//             (489 global tile buckets -> 512-entry hist, 6 KB) ->
//             wave-shfl scan -> one global atomic per (block,tile) ->
//             in-LDS counting sort (hist reused as cursor) -> coalesced
//             run writes (runs avg 16.8 words = 67 B with TILE=2048,
//             halving partial-line RMW vs TILE=1024); bucket id recovered
//             by 9-step binary search. 38 KB LDS -> 4 blocks/CU.
//   K2 csr:   per tile: edges staged in registers (19/thread), local-dst
//             hist[2048] -> 4-elem wave-shfl scan -> counting-sort srcs by
//             local dst, write back in place; then fused node transform
//             hs = (x@W)*dinv bf16 + coalesced pd (ptr,deg int2) write.
//   K3 gather: thread per (node,feature). UNCHANGED (measured 126 us,
//             MSHR-bound ~2.6 TB/s on 252 MB random 64B fetches; flat-8/
//             nontemporal variant measured 143 -> do not touch).
//   shadow:   if ws_size permits, re-run init+bin into scratch (serial,
//             isolated) purely to decode bin's duration from the total
//             next round. Remove once measured.

#define F 16
#define TILE 2048
#define TSHIFT 11
#define NBMAX 512         // >= nbuck = 489 tile buckets
#define CAP 9728          // mean 8192/tile, sd ~90 -> +17 sd headroom
#define EPT 19            // CAP / 512
#define CHUNK 8192
#define CUR_STRIDE 16     // 1 cursor per 64B line

static __device__ __forceinline__ unsigned short f2bf(float f) {
    unsigned u = __float_as_uint(f);
    unsigned r = (u + 0x7FFFu + ((u >> 16) & 1u)) >> 16;
    return (unsigned short)r;
}
static __device__ __forceinline__ float bf2f(unsigned short u) {
    return __uint_as_float(((unsigned)u) << 16);
}

// Exclusive scan of one value per thread across a 512-thread block.
// Wave-level shfl scan + 8-wave combine: 1 barrier. wsum: >=8 ints LDS.
static __device__ __forceinline__ int excl_scan_512(int s, int t, int* wsum) {
    int lane = t & 63, wv = t >> 6;
    int incl = s;
    #pragma unroll
    for (int off = 1; off < 64; off <<= 1) {
        int y = __shfl_up(incl, off, 64);
        if (lane >= off) incl += y;
    }
    if (lane == 63) wsum[wv] = incl;
    __syncthreads();
    int woff = 0;
    #pragma unroll
    for (int w = 0; w < 8; w++) {
        int v = wsum[w];
        if (w < wv) woff += v;
    }
    return woff + incl - s;
}

__global__ void init_kernel(int* __restrict__ cursor, int nbuck) {
    int b = blockIdx.x * blockDim.x + threadIdx.x;
    if (b < nbuck) cursor[b * CUR_STRIDE] = b * CAP;
}

__global__ void __launch_bounds__(512)
bin_kernel(const int* __restrict__ row, const int* __restrict__ col,
           int* __restrict__ cursor, unsigned* __restrict__ adj, int E, int nbuck) {
    __shared__ int hist[NBMAX];       // counts, then running sort cursor
    __shared__ int lstart[NBMAX];     // exclusive prefix (for write phase)
    __shared__ int slotBase[NBMAX];
    __shared__ int wsum[8];
    __shared__ unsigned sortedE[CHUNK];   // 32 KB
    // total ~38 KB -> 4 blocks/CU

    int t = threadIdx.x;
    hist[t] = 0;
    __syncthreads();

    int base = blockIdx.x * CHUNK;
    int nE = E - base; if (nE > CHUNK) nE = CHUNK;

    // stage edges in registers: single global pass over (row,col)
    int c[16], r[16];
    #pragma unroll
    for (int q = 0; q < 16; q++) {
        int i = t + q * 512;
        if (i < nE) {
            c[q] = col[base + i];
            r[q] = row[base + i];
        } else { c[q] = -1; r[q] = 0; }
    }
    #pragma unroll
    for (int q = 0; q < 16; q++)
        if (c[q] >= 0) atomicAdd(&hist[c[q] >> TSHIFT], 1);
    __syncthreads();

    int s = hist[t];
    int excl = excl_scan_512(s, t, wsum);   // one barrier inside
    lstart[t] = excl;
    hist[t]   = excl;                       // reuse as running cursor
    if (s > 0 && t < nbuck)
        slotBase[t] = atomicAdd(&cursor[t * CUR_STRIDE], s);
    __syncthreads();

    #pragma unroll
    for (int q = 0; q < 16; q++) {
        if (c[q] >= 0) {
            int bk = c[q] >> TSHIFT;
            int li = atomicAdd(&hist[bk], 1);          // absolute position
            sortedE[li] = (((unsigned)(c[q] & (TILE - 1))) << 20) | (unsigned)r[q];
        }
    }
    __syncthreads();

    // write phase: recover bucket of position i by binary search over lstart
    // (upper_bound - 1; empty buckets have zero width). lstart[0]==0 <= i.
    for (int i = t; i < nE; i += 512) {
        int lo = 0, hi = NBMAX;
        #pragma unroll
        for (int it = 0; it < 9; it++) {
            int mid = (lo + hi) >> 1;
            if (lstart[mid] <= i) lo = mid; else hi = mid;
        }
        int bk = lo;
        int g = slotBase[bk] + (i - lstart[bk]);
        if (g < (bk + 1) * CAP) adj[g] = sortedE[i];
    }
}

// Per tile: build per-node CSR (sort region by local dst, in place), write
// packed (ptr,deg), then fused node transform hs = (x@W)*dinv (bf16).
__global__ void __launch_bounds__(512)
csr_node_kernel(const int* __restrict__ cursor, unsigned* __restrict__ adj,
                const float* __restrict__ x, const float* __restrict__ W,
                int2* __restrict__ pd, unsigned short* __restrict__ hs, int N) {
    __shared__ unsigned srt[CAP];      // 38 KB sorted srcs
    __shared__ int hist[TILE];         // 8 KB deg counts (preserved)
    __shared__ int lstart[TILE];       // 8 KB
    __shared__ int cnt2[TILE];         // 8 KB running sort cursor
    __shared__ int wsum[8];
    __shared__ float sW[256];
    // total ~63 KB -> 2 blocks/CU

    int t = threadIdx.x, b = blockIdx.x;
    if (t < 256) sW[t] = W[t];
    for (int i = t; i < TILE; i += 512) { hist[i] = 0; cnt2[i] = 0; }
    __syncthreads();

    int base = b * CAP;
    int cnt_total = cursor[b * CUR_STRIDE] - base;
    if (cnt_total > CAP) cnt_total = CAP;

    // stage region in registers (CAP/512 = 19 per thread)
    unsigned e[EPT];
    #pragma unroll
    for (int q = 0; q < EPT; q++) {
        int i = t + q * 512;
        if (i < cnt_total) {
            unsigned ee = adj[base + i];
            e[q] = ee;
            atomicAdd(&hist[ee >> 20], 1);
        } else e[q] = 0xFFFFFFFFu;   // packed values are <= 0x7FFFFFFF
    }
    __syncthreads();

    int a0 = hist[4 * t], a1 = hist[4 * t + 1];
    int a2 = hist[4 * t + 2], a3 = hist[4 * t + 3];
    int s = a0 + a1 + a2 + a3;
    int excl = excl_scan_512(s, t, wsum);
    lstart[4 * t]     = excl;
    lstart[4 * t + 1] = excl + a0;
    lstart[4 * t + 2] = excl + a0 + a1;
    lstart[4 * t + 3] = excl + a0 + a1 + a2;
    __syncthreads();

    // counting-sort srcs by local dst
    #pragma unroll
    for (int q = 0; q < EPT; q++) {
        if (e[q] != 0xFFFFFFFFu) {
            int cl = (int)(e[q] >> 20);
            int pos = lstart[cl] + atomicAdd(&cnt2[cl], 1);
            srt[pos] = e[q] & 0xFFFFFu;
        }
    }
    __syncthreads();
    #pragma unroll
    for (int q = 0; q < EPT; q++) {
        int i = t + q * 512;
        if (i < cnt_total) adj[base + i] = srt[i];   // in-place per-node CSR
    }

    // fused node transform + coalesced pd write (lstart/hist intact)
    #pragma unroll
    for (int p = 0; p < 4; p++) {
        int local = p * 512 + t;
        int node = b * TILE + local;
        if (node >= N) continue;
        int dg = hist[local];
        pd[node] = make_int2(base + lstart[local], dg);
        float di = rsqrtf((float)dg + 1.0f);

        const float4* xr = (const float4*)(x + (size_t)node * F);
        float4 x0 = xr[0], x1 = xr[1], x2 = xr[2], x3 = xr[3];
        float xv[16] = {x0.x, x0.y, x0.z, x0.w, x1.x, x1.y, x1.z, x1.w,
                        x2.x, x2.y, x2.z, x2.w, x3.x, x3.y, x3.z, x3.w};
        float hv[16];
        #pragma unroll
        for (int j = 0; j < 16; j++) hv[j] = 0.f;
        #pragma unroll
        for (int k = 0; k < 16; k++) {
            float xk = xv[k];
            const float4* wr = (const float4*)(sW + k * 16);
            float4 w0 = wr[0], w1 = wr[1], w2 = wr[2], w3 = wr[3];
            hv[0]  += xk * w0.x; hv[1]  += xk * w0.y; hv[2]  += xk * w0.z; hv[3]  += xk * w0.w;
            hv[4]  += xk * w1.x; hv[5]  += xk * w1.y; hv[6]  += xk * w1.z; hv[7]  += xk * w1.w;
            hv[8]  += xk * w2.x; hv[9]  += xk * w2.y; hv[10] += xk * w2.z; hv[11] += xk * w2.w;
            hv[12] += xk * w3.x; hv[13] += xk * w3.y; hv[14] += xk * w3.z; hv[15] += xk * w3.w;
        }
        unsigned pkk[8];
        #pragma unroll
        for (int q = 0; q < 8; q++)
            pkk[q] = (unsigned)f2bf(hv[2*q] * di) | ((unsigned)f2bf(hv[2*q+1] * di) << 16);
        uint4* hp = (uint4*)(hs + (size_t)node * F);
        hp[0] = make_uint4(pkk[0], pkk[1], pkk[2], pkk[3]);
        hp[1] = make_uint4(pkk[4], pkk[5], pkk[6], pkk[7]);
    }
}

__global__ void __launch_bounds__(256)
gather_kernel(const int2* __restrict__ pd, const unsigned* __restrict__ adj,
              const unsigned short* __restrict__ hs, const float* __restrict__ bias,
              float* __restrict__ out, int N) {
    int tid = blockIdx.x * blockDim.x + threadIdx.x;
    int g = tid >> 4;
    int j = tid & 15;
    if (g >= N) return;

    int2 p = pd[g];
    int p0 = p.x, d = p.y;
    int end = p0 + d;

    float a0 = bf2f(hs[(size_t)g * F + j]);   // self-loop term
    float a1 = 0.f;
    int k = p0;
    for (; k + 1 < end; k += 2) {             // 2 independent chains
        unsigned r0 = adj[k];
        unsigned r1 = adj[k + 1];
        a0 += bf2f(hs[(size_t)r0 * F + j]);
        a1 += bf2f(hs[(size_t)r1 * F + j]);
    }
    if (k < end) a1 += bf2f(hs[(size_t)adj[k] * F + j]);

    float di = rsqrtf((float)d + 1.0f);
    out[(size_t)g * F + j] = di * (a0 + a1) + bias[j];
}

extern "C" void kernel_launch(void* const* d_in, const int* in_sizes, int n_in,
                              void* d_out, int out_size, void* d_ws, size_t ws_size,
                              hipStream_t stream) {
    const float* x  = (const float*)d_in[0];
    const int*   ei = (const int*)d_in[1];
    const float* W  = (const float*)d_in[2];
    const float* b  = (const float*)d_in[3];

    int N = in_sizes[0] / F;       // 1,000,000 (< 2^20, required for packing)
    int E = in_sizes[1] / 2;       // 4,000,000
    const int* row = ei;           // src
    const int* col = ei + E;       // dst

    float* out = (float*)d_out;
    int nbuck = (N + TILE - 1) / TILE;   // 489

    auto align_up = [](size_t v) { return (v + 255) & ~(size_t)255; };
    char* ws = (char*)d_ws;
    size_t off = 0;
    int* cursor = (int*)(ws + off);          off = align_up(off + (size_t)nbuck * CUR_STRIDE * 4);
    unsigned* adj = (unsigned*)(ws + off);   off = align_up(off + (size_t)nbuck * CAP * 4);
    int2* pd = (int2*)(ws + off);            off = align_up(off + (size_t)N * 8);
    unsigned short* hs = (unsigned short*)(ws + off); off = align_up(off + (size_t)N * F * 2);
    // ~59 MB live

    init_kernel<<<(nbuck + 255) / 256, 256, 0, stream>>>(cursor, nbuck);
    bin_kernel <<<(E + CHUNK - 1) / CHUNK, 512, 0, stream>>>(row, col, cursor, adj, E, nbuck);
    csr_node_kernel<<<nbuck, 512, 0, stream>>>(cursor, adj, x, W, pd, hs, N);

    long long gthreads = (long long)N * F;
    gather_kernel<<<(int)((gthreads + 255) / 256), 256, 0, stream>>>
        (pd, adj, hs, b, out, N);

    // --- measurement shadow (decode bin duration from total; remove next
    // round): re-run init+bin into scratch. Serial in-stream, touches only
    // scratch memory, result unused.
    size_t cur_bytes = align_up((size_t)nbuck * CUR_STRIDE * 4);
    size_t adj_bytes = align_up((size_t)nbuck * CAP * 4);
    if (ws_size >= off + cur_bytes + adj_bytes) {
        int* cursor2 = (int*)(ws + off);
        unsigned* adj2 = (unsigned*)(ws + off + cur_bytes);
        init_kernel<<<(nbuck + 255) / 256, 256, 0, stream>>>(cursor2, nbuck);
        bin_kernel <<<(E + CHUNK - 1) / CHUNK, 512, 0, stream>>>(row, col, cursor2, adj2, E, nbuck);
    }
}

// Round 5
// 298.805 us; speedup vs baseline: 1.1063x; 1.1063x over previous
//
#include <hip/hip_runtime.h>

// GCNConv forward: out = D^{-1/2} (A + I) D^{-1/2} (x @ W) + b
// N = 1,000,000 nodes (< 2^20), E = 4,000,000 edges, F = 16.
//
// Pipeline (tiles = 2048 consecutive dst nodes, 489 tiles):
//   K0 init:  cursor[b] = b*CAP (line-padded cursors)
//   K1 bin:   per 8192-edge block: edges staged in REGISTERS, LDS hist
//             (489 global tile buckets -> 512-entry hist, 6 KB) ->
//             wave-shfl scan -> one global atomic per (block,tile) ->
//             in-LDS counting sort (hist reused as cursor) -> coalesced
//             run writes (runs avg 16.8 words = 67 B with TILE=2048,
//             halving partial-line RMW vs TILE=1024); bucket id recovered
//             by 9-step binary search. 38 KB LDS -> 4 blocks/CU.
//   K2 csr:   per tile: edges staged in registers (19/thread), local-dst
//             hist[2048] -> 4-elem wave-shfl scan -> counting-sort srcs by
//             local dst, write back in place; then fused node transform
//             hs = (x@W)*dinv bf16 + coalesced pd (ptr,deg int2) write.
//   K3 gather: thread per (node,feature). UNCHANGED (measured 126 us,
//             MSHR-bound ~2.6 TB/s on 252 MB random 64B fetches; flat-8/
//             nontemporal variant measured 143 -> do not touch).
//
//   (round-4 measurement shadow removed: round-5 total vs round-4 total
//    decodes bin = 330.6 - total_now, csr = total_now - 128 - bin - gaps)

#define F 16
#define TILE 2048
#define TSHIFT 11
#define NBMAX 512         // >= nbuck = 489 tile buckets
#define CAP 9728          // mean 8192/tile, sd ~90 -> +17 sd headroom
#define EPT 19            // CAP / 512
#define CHUNK 8192
#define CUR_STRIDE 16     // 1 cursor per 64B line

static __device__ __forceinline__ unsigned short f2bf(float f) {
    unsigned u = __float_as_uint(f);
    unsigned r = (u + 0x7FFFu + ((u >> 16) & 1u)) >> 16;
    return (unsigned short)r;
}
static __device__ __forceinline__ float bf2f(unsigned short u) {
    return __uint_as_float(((unsigned)u) << 16);
}

// Exclusive scan of one value per thread across a 512-thread block.
// Wave-level shfl scan + 8-wave combine: 1 barrier. wsum: >=8 ints LDS.
static __device__ __forceinline__ int excl_scan_512(int s, int t, int* wsum) {
    int lane = t & 63, wv = t >> 6;
    int incl = s;
    #pragma unroll
    for (int off = 1; off < 64; off <<= 1) {
        int y = __shfl_up(incl, off, 64);
        if (lane >= off) incl += y;
    }
    if (lane == 63) wsum[wv] = incl;
    __syncthreads();
    int woff = 0;
    #pragma unroll
    for (int w = 0; w < 8; w++) {
        int v = wsum[w];
        if (w < wv) woff += v;
    }
    return woff + incl - s;
}

__global__ void init_kernel(int* __restrict__ cursor, int nbuck) {
    int b = blockIdx.x * blockDim.x + threadIdx.x;
    if (b < nbuck) cursor[b * CUR_STRIDE] = b * CAP;
}

__global__ void __launch_bounds__(512)
bin_kernel(const int* __restrict__ row, const int* __restrict__ col,
           int* __restrict__ cursor, unsigned* __restrict__ adj, int E, int nbuck) {
    __shared__ int hist[NBMAX];       // counts, then running sort cursor
    __shared__ int lstart[NBMAX];     // exclusive prefix (for write phase)
    __shared__ int slotBase[NBMAX];
    __shared__ int wsum[8];
    __shared__ unsigned sortedE[CHUNK];   // 32 KB
    // total ~38 KB -> 4 blocks/CU

    int t = threadIdx.x;
    hist[t] = 0;
    __syncthreads();

    int base = blockIdx.x * CHUNK;
    int nE = E - base; if (nE > CHUNK) nE = CHUNK;

    // stage edges in registers: single global pass over (row,col)
    int c[16], r[16];
    #pragma unroll
    for (int q = 0; q < 16; q++) {
        int i = t + q * 512;
        if (i < nE) {
            c[q] = col[base + i];
            r[q] = row[base + i];
        } else { c[q] = -1; r[q] = 0; }
    }
    #pragma unroll
    for (int q = 0; q < 16; q++)
        if (c[q] >= 0) atomicAdd(&hist[c[q] >> TSHIFT], 1);
    __syncthreads();

    int s = hist[t];
    int excl = excl_scan_512(s, t, wsum);   // one barrier inside
    lstart[t] = excl;
    hist[t]   = excl;                       // reuse as running cursor
    if (s > 0 && t < nbuck)
        slotBase[t] = atomicAdd(&cursor[t * CUR_STRIDE], s);
    __syncthreads();

    #pragma unroll
    for (int q = 0; q < 16; q++) {
        if (c[q] >= 0) {
            int bk = c[q] >> TSHIFT;
            int li = atomicAdd(&hist[bk], 1);          // absolute position
            sortedE[li] = (((unsigned)(c[q] & (TILE - 1))) << 20) | (unsigned)r[q];
        }
    }
    __syncthreads();

    // write phase: recover bucket of position i by binary search over lstart
    // (upper_bound - 1; empty buckets have zero width). lstart[0]==0 <= i.
    for (int i = t; i < nE; i += 512) {
        int lo = 0, hi = NBMAX;
        #pragma unroll
        for (int it = 0; it < 9; it++) {
            int mid = (lo + hi) >> 1;
            if (lstart[mid] <= i) lo = mid; else hi = mid;
        }
        int bk = lo;
        int g = slotBase[bk] + (i - lstart[bk]);
        if (g < (bk + 1) * CAP) adj[g] = sortedE[i];
    }
}

// Per tile: build per-node CSR (sort region by local dst, in place), write
// packed (ptr,deg), then fused node transform hs = (x@W)*dinv (bf16).
__global__ void __launch_bounds__(512)
csr_node_kernel(const int* __restrict__ cursor, unsigned* __restrict__ adj,
                const float* __restrict__ x, const float* __restrict__ W,
                int2* __restrict__ pd, unsigned short* __restrict__ hs, int N) {
    __shared__ unsigned srt[CAP];      // 38 KB sorted srcs
    __shared__ int hist[TILE];         // 8 KB deg counts (preserved)
    __shared__ int lstart[TILE];       // 8 KB
    __shared__ int cnt2[TILE];         // 8 KB running sort cursor
    __shared__ int wsum[8];
    __shared__ float sW[256];
    // total ~63 KB -> 2 blocks/CU

    int t = threadIdx.x, b = blockIdx.x;
    if (t < 256) sW[t] = W[t];
    for (int i = t; i < TILE; i += 512) { hist[i] = 0; cnt2[i] = 0; }
    __syncthreads();

    int base = b * CAP;
    int cnt_total = cursor[b * CUR_STRIDE] - base;
    if (cnt_total > CAP) cnt_total = CAP;

    // stage region in registers (CAP/512 = 19 per thread)
    unsigned e[EPT];
    #pragma unroll
    for (int q = 0; q < EPT; q++) {
        int i = t + q * 512;
        if (i < cnt_total) {
            unsigned ee = adj[base + i];
            e[q] = ee;
            atomicAdd(&hist[ee >> 20], 1);
        } else e[q] = 0xFFFFFFFFu;   // packed values are <= 0x7FFFFFFF
    }
    __syncthreads();

    int a0 = hist[4 * t], a1 = hist[4 * t + 1];
    int a2 = hist[4 * t + 2], a3 = hist[4 * t + 3];
    int s = a0 + a1 + a2 + a3;
    int excl = excl_scan_512(s, t, wsum);
    lstart[4 * t]     = excl;
    lstart[4 * t + 1] = excl + a0;
    lstart[4 * t + 2] = excl + a0 + a1;
    lstart[4 * t + 3] = excl + a0 + a1 + a2;
    __syncthreads();

    // counting-sort srcs by local dst
    #pragma unroll
    for (int q = 0; q < EPT; q++) {
        if (e[q] != 0xFFFFFFFFu) {
            int cl = (int)(e[q] >> 20);
            int pos = lstart[cl] + atomicAdd(&cnt2[cl], 1);
            srt[pos] = e[q] & 0xFFFFFu;
        }
    }
    __syncthreads();
    #pragma unroll
    for (int q = 0; q < EPT; q++) {
        int i = t + q * 512;
        if (i < cnt_total) adj[base + i] = srt[i];   // in-place per-node CSR
    }

    // fused node transform + coalesced pd write (lstart/hist intact)
    #pragma unroll
    for (int p = 0; p < 4; p++) {
        int local = p * 512 + t;
        int node = b * TILE + local;
        if (node >= N) continue;
        int dg = hist[local];
        pd[node] = make_int2(base + lstart[local], dg);
        float di = rsqrtf((float)dg + 1.0f);

        const float4* xr = (const float4*)(x + (size_t)node * F);
        float4 x0 = xr[0], x1 = xr[1], x2 = xr[2], x3 = xr[3];
        float xv[16] = {x0.x, x0.y, x0.z, x0.w, x1.x, x1.y, x1.z, x1.w,
                        x2.x, x2.y, x2.z, x2.w, x3.x, x3.y, x3.z, x3.w};
        float hv[16];
        #pragma unroll
        for (int j = 0; j < 16; j++) hv[j] = 0.f;
        #pragma unroll
        for (int k = 0; k < 16; k++) {
            float xk = xv[k];
            const float4* wr = (const float4*)(sW + k * 16);
            float4 w0 = wr[0], w1 = wr[1], w2 = wr[2], w3 = wr[3];
            hv[0]  += xk * w0.x; hv[1]  += xk * w0.y; hv[2]  += xk * w0.z; hv[3]  += xk * w0.w;
            hv[4]  += xk * w1.x; hv[5]  += xk * w1.y; hv[6]  += xk * w1.z; hv[7]  += xk * w1.w;
            hv[8]  += xk * w2.x; hv[9]  += xk * w2.y; hv[10] += xk * w2.z; hv[11] += xk * w2.w;
            hv[12] += xk * w3.x; hv[13] += xk * w3.y; hv[14] += xk * w3.z; hv[15] += xk * w3.w;
        }
        unsigned pkk[8];
        #pragma unroll
        for (int q = 0; q < 8; q++)
            pkk[q] = (unsigned)f2bf(hv[2*q] * di) | ((unsigned)f2bf(hv[2*q+1] * di) << 16);
        uint4* hp = (uint4*)(hs + (size_t)node * F);
        hp[0] = make_uint4(pkk[0], pkk[1], pkk[2], pkk[3]);
        hp[1] = make_uint4(pkk[4], pkk[5], pkk[6], pkk[7]);
    }
}

__global__ void __launch_bounds__(256)
gather_kernel(const int2* __restrict__ pd, const unsigned* __restrict__ adj,
              const unsigned short* __restrict__ hs, const float* __restrict__ bias,
              float* __restrict__ out, int N) {
    int tid = blockIdx.x * blockDim.x + threadIdx.x;
    int g = tid >> 4;
    int j = tid & 15;
    if (g >= N) return;

    int2 p = pd[g];
    int p0 = p.x, d = p.y;
    int end = p0 + d;

    float a0 = bf2f(hs[(size_t)g * F + j]);   // self-loop term
    float a1 = 0.f;
    int k = p0;
    for (; k + 1 < end; k += 2) {             // 2 independent chains
        unsigned r0 = adj[k];
        unsigned r1 = adj[k + 1];
        a0 += bf2f(hs[(size_t)r0 * F + j]);
        a1 += bf2f(hs[(size_t)r1 * F + j]);
    }
    if (k < end) a1 += bf2f(hs[(size_t)adj[k] * F + j]);

    float di = rsqrtf((float)d + 1.0f);
    out[(size_t)g * F + j] = di * (a0 + a1) + bias[j];
}

extern "C" void kernel_launch(void* const* d_in, const int* in_sizes, int n_in,
                              void* d_out, int out_size, void* d_ws, size_t ws_size,
                              hipStream_t stream) {
    const float* x  = (const float*)d_in[0];
    const int*   ei = (const int*)d_in[1];
    const float* W  = (const float*)d_in[2];
    const float* b  = (const float*)d_in[3];

    int N = in_sizes[0] / F;       // 1,000,000 (< 2^20, required for packing)
    int E = in_sizes[1] / 2;       // 4,000,000
    const int* row = ei;           // src
    const int* col = ei + E;       // dst

    float* out = (float*)d_out;
    int nbuck = (N + TILE - 1) / TILE;   // 489

    auto align_up = [](size_t v) { return (v + 255) & ~(size_t)255; };
    char* ws = (char*)d_ws;
    size_t off = 0;
    int* cursor = (int*)(ws + off);          off = align_up(off + (size_t)nbuck * CUR_STRIDE * 4);
    unsigned* adj = (unsigned*)(ws + off);   off = align_up(off + (size_t)nbuck * CAP * 4);
    int2* pd = (int2*)(ws + off);            off = align_up(off + (size_t)N * 8);
    unsigned short* hs = (unsigned short*)(ws + off); off = align_up(off + (size_t)N * F * 2);
    // ~59 MB live

    init_kernel<<<(nbuck + 255) / 256, 256, 0, stream>>>(cursor, nbuck);
    bin_kernel <<<(E + CHUNK - 1) / CHUNK, 512, 0, stream>>>(row, col, cursor, adj, E, nbuck);
    csr_node_kernel<<<nbuck, 512, 0, stream>>>(cursor, adj, x, W, pd, hs, N);

    long long gthreads = (long long)N * F;
    gather_kernel<<<(int)((gthreads + 255) / 256), 256, 0, stream>>>
        (pd, adj, hs, b, out, N);
}